// Round 12
// baseline (486.511 us; speedup 1.0000x reference)
//
#include <hip/hip_runtime.h>

#define BB 8
#define LL 1024
#define FF 1024
#define HH 16
#define DD 64
#define NBH 128   // B*H

typedef __attribute__((ext_vector_type(8))) short bf16x8;
typedef __attribute__((ext_vector_type(4))) float f32x4;

#define GLD_LDS16(g, l)                                                        \
  __builtin_amdgcn_global_load_lds(                                            \
      (const __attribute__((address_space(1))) unsigned int*)(g),              \
      (__attribute__((address_space(3))) unsigned int*)(l), 16, 0, 0)

__device__ __forceinline__ unsigned short f2bf(float f) {
  unsigned int u = __float_as_uint(f);
  unsigned int r = u + 0x7fffu + ((u >> 16) & 1u);   // RNE
  return (unsigned short)(r >> 16);
}
__device__ __forceinline__ float bf2f(unsigned short s) {
  return __uint_as_float(((unsigned int)s) << 16);
}

// ---------------- fp32 -> bf16 convert (ALL inputs, one launch) -------------
__global__ __launch_bounds__(256) void cvt_all(
    const float* __restrict__ q, const float* __restrict__ k,
    const float* __restrict__ v, const float* __restrict__ w0,
    const float* __restrict__ w1, const float* __restrict__ w2,
    const float* __restrict__ w3, short* __restrict__ dst) {
  const int NA = (BB * LL * FF) / 4;  // 2^21 float4 per activation
  const int NW = (FF * FF) / 4;       // 2^18 float4 per weight
  int i = blockIdx.x * 256 + threadIdx.x;   // exact grid
  const float* src;
  int off;
  if (i < 3 * NA) {
    int z = i >> 21;
    src = (z == 0) ? q : (z == 1) ? k : v;
    off = i - z * NA;
  } else {
    int j = i - 3 * NA;
    int z = j >> 18;
    src = (z == 0) ? w0 : (z == 1) ? w1 : (z == 2) ? w2 : w3;
    off = j - z * NW;
  }
  f32x4 val = __builtin_nontemporal_load((const f32x4*)src + off);
  short4 o;
  o.x = (short)f2bf(val[0]); o.y = (short)f2bf(val[1]);
  o.z = (short)f2bf(val[2]); o.w = (short)f2bf(val[3]);
  ((short4*)dst)[i] = o;
}

// ---------------- QKV projection GEMM (NT, bf16 MFMA, BK=64) ----------------
__global__ __launch_bounds__(256) void proj_qkv(
    const short* __restrict__ Aall, const short* __restrict__ Wall,
    const float* __restrict__ bq, const float* __restrict__ bk,
    const float* __restrict__ bv, short* __restrict__ Dall) {
  const int o = blockIdx.x + (blockIdx.y << 6) + (blockIdx.z << 9);
  const int n = ((o & 7) * 192) + (o >> 3);
  const int z = n >> 9;
  const int r = n & 511;
  const int by = r & 7, bx = r >> 3;

  const short* A  = Aall + (size_t)z * (BB * LL * FF);
  const short* Bt = Wall + (size_t)z * (FF * FF);
  const float* bias = (z == 0) ? bq : (z == 1) ? bk : bv;
  short* dst = Dall + (size_t)z * ((size_t)NBH * LL * DD);
  // fold 1/sqrt(D) AND log2(e) into Q so softmax uses native exp2
  const float scale = (z == 0) ? 0.125f * 1.44269504088896f : 1.0f;

  __shared__ __attribute__((aligned(16))) short LB[128 * 136];  // 34 KB
  short* As = LB;            // [128][64] swizzled
  short* Bs = LB + 128 * 64; // [128][64] swizzled

  const int tid = threadIdx.x;
  const int lane = tid & 63, w = tid >> 6;
  const int wr = w >> 1, wc = w & 1;
  const int row16 = lane & 15, kg = lane >> 4;
  const int m0 = bx * 128, n0 = by * 128;

  const f32x4 z4 = {0.f, 0.f, 0.f, 0.f};
  f32x4 acc[4][4];
  for (int i = 0; i < 4; ++i)
    for (int j = 0; j < 4; ++j) acc[i][j] = z4;

  for (int k0 = 0; k0 < FF; k0 += 64) {
#pragma unroll
    for (int rr = 0; rr < 4; ++rr) {
      int e8 = tid + rr * 256;
      int row = e8 >> 3, cs = ((e8 & 7) ^ (row & 7)) * 8;
      GLD_LDS16(A + (size_t)(m0 + row) * FF + k0 + cs, As + e8 * 8);
      GLD_LDS16(Bt + (size_t)(n0 + row) * FF + k0 + cs, Bs + e8 * 8);
    }
    __syncthreads();
#pragma unroll
    for (int kk2 = 0; kk2 < 2; ++kk2) {
      bf16x8 af[4], bfr[4];
#pragma unroll
      for (int i = 0; i < 4; ++i) {
        int ra = wr * 64 + i * 16 + row16;
        int rb = wc * 64 + i * 16 + row16;
        af[i]  = *(const bf16x8*)(As + ra * 64 + ((((kk2 << 2) | kg) ^ (ra & 7)) << 3));
        bfr[i] = *(const bf16x8*)(Bs + rb * 64 + ((((kk2 << 2) | kg) ^ (rb & 7)) << 3));
      }
#pragma unroll
      for (int i = 0; i < 4; ++i)
#pragma unroll
        for (int j = 0; j < 4; ++j)
          acc[i][j] = __builtin_amdgcn_mfma_f32_16x16x32_bf16(af[i], bfr[j], acc[i][j], 0, 0, 0);
    }
    __syncthreads();
  }

  // ---- epilogue through LDS tile LB[128][136] ----
  const int z2 = (z == 2);
#pragma unroll
  for (int i = 0; i < 4; ++i) {
#pragma unroll
    for (int j = 0; j < 4; ++j) {
      int nl = wc * 64 + j * 16 + row16;
      float bn = bias[n0 + nl];
#pragma unroll
      for (int rr = 0; rr < 4; ++rr) {
        int ml = wr * 64 + i * 16 + kg * 4 + rr;
        float val = (acc[i][j][rr] + bn) * scale;
        int rrow = z2 ? nl : ml, ccol = z2 ? ml : nl;
        LB[rrow * 136 + ccol] = (short)f2bf(val);
      }
    }
  }
  __syncthreads();
  const int b = m0 >> 10;
  const int lbase = m0 & 1023;
#pragma unroll
  for (int rr = 0; rr < 8; ++rr) {
    int e = tid + rr * 256;          // 0..2047
    int row = e >> 4, c8 = e & 15;
    uint4 val = *(const uint4*)(LB + row * 136 + c8 * 8);
    if (!z2) {
      int l = lbase + row;
      int h = (n0 + c8 * 8) >> 6, d = (c8 & 7) * 8;
      *(uint4*)(dst + (((size_t)(b * HH + h)) * LL + l) * DD + d) = val;
    } else {
      int h = (n0 + row) >> 6, d = (n0 + row) & 63;
      int l = lbase + c8 * 8;
      *(uint4*)(dst + (((size_t)(b * HH + h)) * DD + d) * LL + l) = val;
    }
  }
}

// ---------------- fused attention (per (bh, 64-row q-block)) ----------------
// DE-STAGED: K/V per bh are L2-resident (128 KB each, XCD-swizzled working
// set ~4 MB) and the MFMA fragment pattern reads 16 full 64B lines per
// instruction — so Q/K/V fragments are read DIRECTLY from global (L1/L2),
// no LDS staging, NO barriers anywhere. Only PsT (8 KB, wave-private)
// remains for the P^T operand transpose. Waves pipeline independently;
// nt Patt stores never block. Arithmetic identical to R9.
__global__ __launch_bounds__(256) void attn_kernel(
    const short* __restrict__ Qh, const short* __restrict__ Kh,
    const short* __restrict__ Vt, float* __restrict__ Patt,
    short* __restrict__ attb) {
  const int o = blockIdx.x + (blockIdx.y << 4);
  const int n = ((o & 7) << 8) + (o >> 3);
  const int bh = n >> 4;
  const int q0 = (n & 15) * 64;
  const int tid = threadIdx.x;
  const int lane = tid & 63, w = tid >> 6;
  const int row16 = lane & 15, kg = lane >> 4;

  __shared__ __attribute__((aligned(16))) short PsT[4][16 * 64];  // 8 KB

  const int qrow = w * 16 + row16;
  const short* qp = Qh + ((size_t)bh * LL + q0 + qrow) * DD;
  bf16x8 aq0 = *(const bf16x8*)(qp + kg * 8);
  bf16x8 aq1 = *(const bf16x8*)(qp + 32 + kg * 8);

  const short* Kb = Kh + (size_t)bh * LL * DD;
  const short* Vb = Vt + (size_t)bh * DD * LL;

  const f32x4 z4 = {0.f, 0.f, 0.f, 0.f};
  float lsum = 0.f;

  // phase 1: row sums of exp2(S') — direct K reads, no barriers
#pragma unroll 2
  for (int t = 0; t < 16; ++t) {
    f32x4 s[4] = {z4, z4, z4, z4};
    __builtin_amdgcn_s_setprio(1);
#pragma unroll
    for (int tt = 0; tt < 4; ++tt) {
      const short* kp = Kb + (size_t)(t * 64 + tt * 16 + row16) * DD;
      bf16x8 b0 = *(const bf16x8*)(kp + kg * 8);
      bf16x8 b1 = *(const bf16x8*)(kp + 32 + kg * 8);
      s[tt] = __builtin_amdgcn_mfma_f32_16x16x32_bf16(b0, aq0, s[tt], 0, 0, 0);
      s[tt] = __builtin_amdgcn_mfma_f32_16x16x32_bf16(b1, aq1, s[tt], 0, 0, 0);
    }
    __builtin_amdgcn_s_setprio(0);
#pragma unroll
    for (int tt = 0; tt < 4; ++tt)
#pragma unroll
      for (int rr = 0; rr < 4; ++rr) lsum += exp2f(s[tt][rr]);
  }
  lsum += __shfl_xor(lsum, 16);
  lsum += __shfl_xor(lsum, 32);
  const float lc = __log2f(lsum);   // normalize inside the exponent

  f32x4 oT[4] = {z4, z4, z4, z4};
  const int qq = q0 + qrow;

  // phase 2: recompute S^T, P = exp2(s - lc), nt-store Patt, O^T += V^T P
#pragma unroll 2
  for (int t = 0; t < 16; ++t) {
    const int k0 = t * 64;
    f32x4 s[4] = {z4, z4, z4, z4};
    __builtin_amdgcn_s_setprio(1);
#pragma unroll
    for (int tt = 0; tt < 4; ++tt) {
      const short* kp = Kb + (size_t)(k0 + tt * 16 + row16) * DD;
      bf16x8 b0 = *(const bf16x8*)(kp + kg * 8);
      bf16x8 b1 = *(const bf16x8*)(kp + 32 + kg * 8);
      s[tt] = __builtin_amdgcn_mfma_f32_16x16x32_bf16(b0, aq0, s[tt], 0, 0, 0);
      s[tt] = __builtin_amdgcn_mfma_f32_16x16x32_bf16(b1, aq1, s[tt], 0, 0, 0);
    }
    __builtin_amdgcn_s_setprio(0);
#pragma unroll
    for (int tt = 0; tt < 4; ++tt) {
      f32x4 pv;
#pragma unroll
      for (int rr = 0; rr < 4; ++rr) pv[rr] = exp2f(s[tt][rr] - lc);
      __builtin_nontemporal_store(
          pv, (f32x4*)(Patt + ((size_t)bh * LL + qq) * LL + k0 + tt * 16 + kg * 4));
      short4 ps;
      ps.x = (short)f2bf(pv[0]); ps.y = (short)f2bf(pv[1]);
      ps.z = (short)f2bf(pv[2]); ps.w = (short)f2bf(pv[3]);
      int c = ((tt * 2 + (kg >> 1)) ^ (row16 & 7));
      *(short4*)(&PsT[w][row16 * 64 + c * 8 + (kg & 1) * 4]) = ps;
    }
    bf16x8 pb0 = *(const bf16x8*)(&PsT[w][row16 * 64 + ((kg ^ (row16 & 7)) << 3)]);
    bf16x8 pb1 = *(const bf16x8*)(&PsT[w][row16 * 64 + (((4 + kg) ^ (row16 & 7)) << 3)]);
    __builtin_amdgcn_s_setprio(1);
#pragma unroll
    for (int td = 0; td < 4; ++td) {
      const short* vp = Vb + (size_t)(td * 16 + row16) * LL + k0;
      bf16x8 v0 = *(const bf16x8*)(vp + kg * 8);
      bf16x8 v1 = *(const bf16x8*)(vp + 32 + kg * 8);
      oT[td] = __builtin_amdgcn_mfma_f32_16x16x32_bf16(v0, pb0, oT[td], 0, 0, 0);
      oT[td] = __builtin_amdgcn_mfma_f32_16x16x32_bf16(v1, pb1, oT[td], 0, 0, 0);
    }
    __builtin_amdgcn_s_setprio(0);
  }

  // reference's bug-compatible recombine: n=bh -> i=n>>3 (n//B), jb=n&7 (n%B)
  const int iblk = bh >> 3;
  const int jb = bh & 7;
#pragma unroll
  for (int td = 0; td < 4; ++td) {
    short4 ov;
    ov.x = (short)f2bf(oT[td][0]); ov.y = (short)f2bf(oT[td][1]);
    ov.z = (short)f2bf(oT[td][2]); ov.w = (short)f2bf(oT[td][3]);
    *(short4*)(attb + ((size_t)jb * LL + qq) * FF + iblk * 64 + td * 16 + kg * 4) = ov;
  }
}

// ---------------- out projection + bias + residual (BK=64) ------------------
__global__ __launch_bounds__(256) void proj_out(
    const short* __restrict__ A, const short* __restrict__ Bt,
    const float* __restrict__ bias, const short* __restrict__ resid,
    short* __restrict__ xb) {
  const int o = blockIdx.x + (blockIdx.y << 6);
  const int n = ((o & 7) << 6) + (o >> 3);
  const int by = n & 7, bx = n >> 3;

  __shared__ __attribute__((aligned(16))) short As[128 * 64];
  __shared__ __attribute__((aligned(16))) short Bs[128 * 64];

  const int tid = threadIdx.x;
  const int lane = tid & 63, w = tid >> 6;
  const int wr = w >> 1, wc = w & 1;
  const int row16 = lane & 15, kg = lane >> 4;
  const int m0 = bx * 128, n0 = by * 128;

  const f32x4 z4 = {0.f, 0.f, 0.f, 0.f};
  f32x4 acc[4][4];
  for (int i = 0; i < 4; ++i)
    for (int j = 0; j < 4; ++j) acc[i][j] = z4;

  for (int k0 = 0; k0 < FF; k0 += 64) {
#pragma unroll
    for (int rr = 0; rr < 4; ++rr) {
      int e8 = tid + rr * 256;
      int row = e8 >> 3, cs = ((e8 & 7) ^ (row & 7)) * 8;
      GLD_LDS16(A + (size_t)(m0 + row) * FF + k0 + cs, As + e8 * 8);
      GLD_LDS16(Bt + (size_t)(n0 + row) * FF + k0 + cs, Bs + e8 * 8);
    }
    __syncthreads();
#pragma unroll
    for (int kk2 = 0; kk2 < 2; ++kk2) {
      bf16x8 af[4], bfr[4];
#pragma unroll
      for (int i = 0; i < 4; ++i) {
        int ra = wr * 64 + i * 16 + row16;
        int rb = wc * 64 + i * 16 + row16;
        af[i]  = *(const bf16x8*)(As + ra * 64 + ((((kk2 << 2) | kg) ^ (ra & 7)) << 3));
        bfr[i] = *(const bf16x8*)(Bs + rb * 64 + ((((kk2 << 2) | kg) ^ (rb & 7)) << 3));
      }
#pragma unroll
      for (int i = 0; i < 4; ++i)
#pragma unroll
        for (int j = 0; j < 4; ++j)
          acc[i][j] = __builtin_amdgcn_mfma_f32_16x16x32_bf16(af[i], bfr[j], acc[i][j], 0, 0, 0);
    }
    __syncthreads();
  }

#pragma unroll
  for (int i = 0; i < 4; ++i) {
#pragma unroll
    for (int j = 0; j < 4; ++j) {
      int ncol = n0 + wc * 64 + j * 16 + row16;
      float bn = bias[ncol];
#pragma unroll
      for (int rr = 0; rr < 4; ++rr) {
        int m = m0 + wr * 64 + i * 16 + kg * 4 + rr;
        float val = acc[i][j][rr] + bn + bf2f((unsigned short)resid[(size_t)m * FF + ncol]);
        xb[(size_t)m * FF + ncol] = (short)f2bf(val);
      }
    }
  }
}

// ---------------- LayerNorm (bf16 input, fp32 output, nt stores) ------------
__global__ __launch_bounds__(256) void ln_kernel(const short* __restrict__ xb,
                                                 const float* __restrict__ gamma,
                                                 const float* __restrict__ beta,
                                                 float* __restrict__ out) {
  const int row = blockIdx.x;
  const int tid = threadIdx.x;
  const short4 v4 = *(const short4*)(xb + (size_t)row * FF + tid * 4);
  float vx = bf2f((unsigned short)v4.x), vy = bf2f((unsigned short)v4.y);
  float vz = bf2f((unsigned short)v4.z), vw = bf2f((unsigned short)v4.w);
  float s = vx + vy + vz + vw;
  float s2 = vx * vx + vy * vy + vz * vz + vw * vw;
#pragma unroll
  for (int o = 1; o < 64; o <<= 1) {
    s += __shfl_xor(s, o);
    s2 += __shfl_xor(s2, o);
  }
  __shared__ float ss[4], ss2[4];
  int w = tid >> 6, lane = tid & 63;
  if (lane == 0) { ss[w] = s; ss2[w] = s2; }
  __syncthreads();
  s = ss[0] + ss[1] + ss[2] + ss[3];
  s2 = ss2[0] + ss2[1] + ss2[2] + ss2[3];
  float mu = s * (1.0f / 1024.0f);
  float var = s2 * (1.0f / 1024.0f) - mu * mu;
  float rs = rsqrtf(var + 1e-5f);
  float4 g = *(const float4*)(gamma + tid * 4);
  float4 be = *(const float4*)(beta + tid * 4);
  f32x4 o;
  o[0] = (vx - mu) * rs * g.x + be.x;
  o[1] = (vy - mu) * rs * g.y + be.y;
  o[2] = (vz - mu) * rs * g.z + be.z;
  o[3] = (vw - mu) * rs * g.w + be.w;
  __builtin_nontemporal_store(o, (f32x4*)(out + (size_t)row * FF + tid * 4));
}

extern "C" void kernel_launch(void* const* d_in, const int* in_sizes, int n_in,
                              void* d_out, int out_size, void* d_ws, size_t ws_size,
                              hipStream_t stream) {
  const float* q  = (const float*)d_in[0];
  const float* k  = (const float*)d_in[1];
  const float* v  = (const float*)d_in[2];
  const float* Wq = (const float*)d_in[3];
  const float* bq = (const float*)d_in[4];
  const float* Wk = (const float*)d_in[5];
  const float* bk = (const float*)d_in[6];
  const float* Wv = (const float*)d_in[7];
  const float* bv = (const float*)d_in[8];
  const float* Wf = (const float*)d_in[9];
  const float* bf = (const float*)d_in[10];
  const float* gamma = (const float*)d_in[11];
  const float* beta  = (const float*)d_in[12];

  float* out = (float*)d_out;
  float* Patt = out + (size_t)BB * LL * FF;  // raw_att at offset 8M floats

  char* ws = (char*)d_ws;
  const size_t MB = (size_t)1 << 20;
  short* qb = (short*)(ws + 0 * MB);     // [B*L][F] bf16 (x3); qb stays live (residual)
  short* Wb = (short*)(ws + 48 * MB);    // 4 x F*F bf16 (contiguous after activations)
  short* Qh = (short*)(ws + 56 * MB);    // [BH][L][D] bf16
  short* Kh = (short*)(ws + 72 * MB);    // [BH][L][D] bf16
  short* Vt = (short*)(ws + 88 * MB);    // [BH][D][L] bf16 (written by proj z=2)
  short* attb = (short*)(ws + 32 * MB);  // reuse v-bf16 region (dead after proj)
  short* xb = (short*)(ws + 16 * MB);    // reuse k-bf16 region (dead after proj)

  // one fused conversion launch: 3*2^21 + 4*2^18 = 7340032 float4 = 28672 blocks
  cvt_all<<<28672, 256, 0, stream>>>(q, k, v, Wq, Wk, Wv, Wf, qb);

  proj_qkv<<<dim3(64, 8, 3), 256, 0, stream>>>(qb, Wb, bq, bk, bv, Qh);
  attn_kernel<<<dim3(16, 128), 256, 0, stream>>>(Qh, Kh, Vt, Patt, attb);
  proj_out<<<dim3(64, 8), 256, 0, stream>>>(attb, Wb + 3 * (size_t)FF * FF, bf, qb, xb);
  ln_kernel<<<8192, 256, 0, stream>>>(xb, gamma, beta, out);
}

// Round 13
// 289.130 us; speedup vs baseline: 1.6827x; 1.6827x over previous
//
#include <hip/hip_runtime.h>

#define BB 8
#define LL 1024
#define FF 1024
#define HH 16
#define DD 64
#define NBH 128   // B*H

typedef __attribute__((ext_vector_type(8))) short bf16x8;
typedef __attribute__((ext_vector_type(4))) float f32x4;

#define GLD_LDS16(g, l)                                                        \
  __builtin_amdgcn_global_load_lds(                                            \
      (const __attribute__((address_space(1))) unsigned int*)(g),              \
      (__attribute__((address_space(3))) unsigned int*)(l), 16, 0, 0)

__device__ __forceinline__ unsigned short f2bf(float f) {
  unsigned int u = __float_as_uint(f);
  unsigned int r = u + 0x7fffu + ((u >> 16) & 1u);   // RNE
  return (unsigned short)(r >> 16);
}
__device__ __forceinline__ float bf2f(unsigned short s) {
  return __uint_as_float(((unsigned int)s) << 16);
}

// ---------------- fp32 -> bf16 convert (ALL inputs, one launch) -------------
__global__ __launch_bounds__(256) void cvt_all(
    const float* __restrict__ q, const float* __restrict__ k,
    const float* __restrict__ v, const float* __restrict__ w0,
    const float* __restrict__ w1, const float* __restrict__ w2,
    const float* __restrict__ w3, short* __restrict__ dst) {
  const int NA = (BB * LL * FF) / 4;  // 2^21 float4 per activation
  const int NW = (FF * FF) / 4;       // 2^18 float4 per weight
  int i = blockIdx.x * 256 + threadIdx.x;   // exact grid
  const float* src;
  int off;
  if (i < 3 * NA) {
    int z = i >> 21;
    src = (z == 0) ? q : (z == 1) ? k : v;
    off = i - z * NA;
  } else {
    int j = i - 3 * NA;
    int z = j >> 18;
    src = (z == 0) ? w0 : (z == 1) ? w1 : (z == 2) ? w2 : w3;
    off = j - z * NW;
  }
  f32x4 val = __builtin_nontemporal_load((const f32x4*)src + off);
  short4 o;
  o.x = (short)f2bf(val[0]); o.y = (short)f2bf(val[1]);
  o.z = (short)f2bf(val[2]); o.w = (short)f2bf(val[3]);
  ((short4*)dst)[i] = o;
}

// ---------------- QKV projection GEMM (NT, bf16 MFMA, BK=64) ----------------
// XCD swizzle (T1); BK=64. Epilogue stages C through a padded LDS tile for
// coalesced b128 stores; z==2 writes the tile TRANSPOSED so V lands directly
// in [bh][d][l] layout.
__global__ __launch_bounds__(256) void proj_qkv(
    const short* __restrict__ Aall, const short* __restrict__ Wall,
    const float* __restrict__ bq, const float* __restrict__ bk,
    const float* __restrict__ bv, short* __restrict__ Dall) {
  const int o = blockIdx.x + (blockIdx.y << 6) + (blockIdx.z << 9);
  const int n = ((o & 7) * 192) + (o >> 3);
  const int z = n >> 9;
  const int r = n & 511;
  const int by = r & 7, bx = r >> 3;

  const short* A  = Aall + (size_t)z * (BB * LL * FF);
  const short* Bt = Wall + (size_t)z * (FF * FF);
  const float* bias = (z == 0) ? bq : (z == 1) ? bk : bv;
  short* dst = Dall + (size_t)z * ((size_t)NBH * LL * DD);
  // fold 1/sqrt(D) AND log2(e) into Q so softmax uses native exp2
  const float scale = (z == 0) ? 0.125f * 1.44269504088896f : 1.0f;

  __shared__ __attribute__((aligned(16))) short LB[128 * 136];  // 34 KB
  short* As = LB;            // [128][64] swizzled
  short* Bs = LB + 128 * 64; // [128][64] swizzled

  const int tid = threadIdx.x;
  const int lane = tid & 63, w = tid >> 6;
  const int wr = w >> 1, wc = w & 1;
  const int row16 = lane & 15, kg = lane >> 4;
  const int m0 = bx * 128, n0 = by * 128;

  const f32x4 z4 = {0.f, 0.f, 0.f, 0.f};
  f32x4 acc[4][4];
  for (int i = 0; i < 4; ++i)
    for (int j = 0; j < 4; ++j) acc[i][j] = z4;

  for (int k0 = 0; k0 < FF; k0 += 64) {
#pragma unroll
    for (int rr = 0; rr < 4; ++rr) {
      int e8 = tid + rr * 256;
      int row = e8 >> 3, cs = ((e8 & 7) ^ (row & 7)) * 8;
      GLD_LDS16(A + (size_t)(m0 + row) * FF + k0 + cs, As + e8 * 8);
      GLD_LDS16(Bt + (size_t)(n0 + row) * FF + k0 + cs, Bs + e8 * 8);
    }
    __syncthreads();
#pragma unroll
    for (int kk2 = 0; kk2 < 2; ++kk2) {
      bf16x8 af[4], bfr[4];
#pragma unroll
      for (int i = 0; i < 4; ++i) {
        int ra = wr * 64 + i * 16 + row16;
        int rb = wc * 64 + i * 16 + row16;
        af[i]  = *(const bf16x8*)(As + ra * 64 + ((((kk2 << 2) | kg) ^ (ra & 7)) << 3));
        bfr[i] = *(const bf16x8*)(Bs + rb * 64 + ((((kk2 << 2) | kg) ^ (rb & 7)) << 3));
      }
#pragma unroll
      for (int i = 0; i < 4; ++i)
#pragma unroll
        for (int j = 0; j < 4; ++j)
          acc[i][j] = __builtin_amdgcn_mfma_f32_16x16x32_bf16(af[i], bfr[j], acc[i][j], 0, 0, 0);
    }
    __syncthreads();
  }

  // ---- epilogue through LDS tile LB[128][136] ----
  const int z2 = (z == 2);
#pragma unroll
  for (int i = 0; i < 4; ++i) {
#pragma unroll
    for (int j = 0; j < 4; ++j) {
      int nl = wc * 64 + j * 16 + row16;
      float bn = bias[n0 + nl];
#pragma unroll
      for (int rr = 0; rr < 4; ++rr) {
        int ml = wr * 64 + i * 16 + kg * 4 + rr;
        float val = (acc[i][j][rr] + bn) * scale;
        int rrow = z2 ? nl : ml, ccol = z2 ? ml : nl;
        LB[rrow * 136 + ccol] = (short)f2bf(val);
      }
    }
  }
  __syncthreads();
  const int b = m0 >> 10;
  const int lbase = m0 & 1023;
#pragma unroll
  for (int rr = 0; rr < 8; ++rr) {
    int e = tid + rr * 256;          // 0..2047
    int row = e >> 4, c8 = e & 15;
    uint4 val = *(const uint4*)(LB + row * 136 + c8 * 8);
    if (!z2) {
      int l = lbase + row;
      int h = (n0 + c8 * 8) >> 6, d = (c8 & 7) * 8;
      *(uint4*)(dst + (((size_t)(b * HH + h)) * LL + l) * DD + d) = val;
    } else {
      int h = (n0 + row) >> 6, d = (n0 + row) & 63;
      int l = lbase + c8 * 8;
      *(uint4*)(dst + (((size_t)(b * HH + h)) * DD + d) * LL + l) = val;
    }
  }
}

// ---------------- fused attention (per (bh, 64-row q-block)) ----------------
// R9 structure (best known): LDS staging is the fetch-amplification filter
// (R12 counter-proof: de-staged = 24.6 GB FETCH, 50x ideal). S^T design;
// XCD swizzle; exp2 softmax; nt Patt stores; phase 1 = 2-deep K prefetch
// over 3 buffers w/ counted vmcnt(2); phase 2 = 1-deep K/V dbuf w/ vmcnt(4)
// (stores ride across barrier); T5 setprio.
__global__ __launch_bounds__(256) void attn_kernel(
    const short* __restrict__ Qh, const short* __restrict__ Kh,
    const short* __restrict__ Vt, float* __restrict__ Patt,
    short* __restrict__ attb) {
  const int o = blockIdx.x + (blockIdx.y << 4);
  const int n = ((o & 7) << 8) + (o >> 3);
  const int bh = n >> 4;
  const int q0 = (n & 15) * 64;
  const int tid = threadIdx.x;
  const int lane = tid & 63, w = tid >> 6;
  const int row16 = lane & 15, kg = lane >> 4;

  __shared__ __attribute__((aligned(16))) short Qs[64 * 64];
  __shared__ __attribute__((aligned(16))) short Ks[2][64 * 64];
  __shared__ __attribute__((aligned(16))) short Vts[2][64 * 64];
  __shared__ __attribute__((aligned(16))) short PsT[4][16 * 64];

  // phase-1 K triple-buffer: slot 2 borrows Vts[0] (unused in phase 1)
  auto kbuf3 = [&](int i) -> short* {
    return (i == 2) ? &Vts[0][0] : &Ks[i][0];
  };

#define STAGE_K(tt, dstp)                                                      \
  {                                                                            \
    int e8a = tid, rowa = e8a >> 3, c8a = (e8a & 7) ^ (rowa & 7);              \
    GLD_LDS16(Kh + ((size_t)bh * LL + (tt) * 64 + rowa) * DD + c8a * 8,        \
              (dstp) + e8a * 8);                                               \
    int e8b = tid + 256, rowb = e8b >> 3, c8b = (e8b & 7) ^ (rowb & 7);        \
    GLD_LDS16(Kh + ((size_t)bh * LL + (tt) * 64 + rowb) * DD + c8b * 8,        \
              (dstp) + e8b * 8);                                               \
  }
#define STAGE_V(tt, dstp)                                                      \
  {                                                                            \
    int e8a = tid, rowa = e8a >> 3, c8a = (e8a & 7) ^ (rowa & 7);              \
    GLD_LDS16(Vt + ((size_t)bh * DD + rowa) * LL + (tt) * 64 + c8a * 8,        \
              (dstp) + e8a * 8);                                               \
    int e8b = tid + 256, rowb = e8b >> 3, c8b = (e8b & 7) ^ (rowb & 7);        \
    GLD_LDS16(Vt + ((size_t)bh * DD + rowb) * LL + (tt) * 64 + c8b * 8,        \
              (dstp) + e8b * 8);                                               \
  }

  {  // Q stage (2 ops) + K tile0 (2) + K tile1 (2)
    int e8a = tid, rowa = e8a >> 3, c8a = (e8a & 7) ^ (rowa & 7);
    GLD_LDS16(Qh + ((size_t)bh * LL + q0 + rowa) * DD + c8a * 8, Qs + e8a * 8);
    int e8b = tid + 256, rowb = e8b >> 3, c8b = (e8b & 7) ^ (rowb & 7);
    GLD_LDS16(Qh + ((size_t)bh * LL + q0 + rowb) * DD + c8b * 8, Qs + e8b * 8);
  }
  STAGE_K(0, kbuf3(0));
  STAGE_K(1, kbuf3(1));
  // need Q + K0 complete; K1's 2 ops may stay outstanding
  asm volatile("s_waitcnt vmcnt(2)" ::: "memory");
  __builtin_amdgcn_s_barrier();

  const int qrow = w * 16 + row16;
  bf16x8 aq0 = *(const bf16x8*)(Qs + qrow * 64 + ((kg ^ (qrow & 7)) << 3));
  bf16x8 aq1 = *(const bf16x8*)(Qs + qrow * 64 + (((kg + 4) ^ (qrow & 7)) << 3));

  const f32x4 z4 = {0.f, 0.f, 0.f, 0.f};
  float lsum = 0.f;

  // phase 1: row sums of exp2(S') — 2-deep prefetch
  for (int t = 0; t < 16; ++t) {
    const short* kb = kbuf3(t % 3);
    if (t < 14) {
      short* kd = kbuf3((t + 2) % 3);
      STAGE_K(t + 2, kd);
    }
    f32x4 s[4] = {z4, z4, z4, z4};
    __builtin_amdgcn_s_setprio(1);
#pragma unroll
    for (int tt = 0; tt < 4; ++tt) {
      int krow = tt * 16 + row16;
      bf16x8 b0 = *(const bf16x8*)(kb + krow * 64 + ((kg ^ (krow & 7)) << 3));
      bf16x8 b1 = *(const bf16x8*)(kb + krow * 64 + (((kg + 4) ^ (krow & 7)) << 3));
      s[tt] = __builtin_amdgcn_mfma_f32_16x16x32_bf16(b0, aq0, s[tt], 0, 0, 0);
      s[tt] = __builtin_amdgcn_mfma_f32_16x16x32_bf16(b1, aq1, s[tt], 0, 0, 0);
    }
    __builtin_amdgcn_s_setprio(0);
#pragma unroll
    for (int tt = 0; tt < 4; ++tt)
#pragma unroll
      for (int rr = 0; rr < 4; ++rr) lsum += exp2f(s[tt][rr]);
    if (t < 14) {
      asm volatile("s_waitcnt vmcnt(2)" ::: "memory");   // t+1 ready, t+2 in flight
    } else {
      asm volatile("s_waitcnt vmcnt(0)" ::: "memory");
    }
    __builtin_amdgcn_s_barrier();
  }
  lsum += __shfl_xor(lsum, 16);
  lsum += __shfl_xor(lsum, 32);
  const float lc = __log2f(lsum);   // normalize inside the exponent

  f32x4 oT[4] = {z4, z4, z4, z4};

  // phase 2: recompute S^T, P = exp2(s - lc), nt-store Patt, O^T += V^T P
  STAGE_K(0, &Ks[0][0]);
  STAGE_V(0, &Vts[0][0]);
  asm volatile("s_waitcnt vmcnt(0)" ::: "memory");
  __builtin_amdgcn_s_barrier();
  for (int t = 0; t < 16; ++t) {
    const int cur = t & 1;
    if (t < 15) {
      STAGE_K(t + 1, &Ks[cur ^ 1][0]);
      STAGE_V(t + 1, &Vts[cur ^ 1][0]);
    }
    f32x4 s[4] = {z4, z4, z4, z4};
    __builtin_amdgcn_s_setprio(1);
#pragma unroll
    for (int tt = 0; tt < 4; ++tt) {
      int krow = tt * 16 + row16;
      bf16x8 b0 = *(const bf16x8*)(&Ks[cur][krow * 64 + ((kg ^ (krow & 7)) << 3)]);
      bf16x8 b1 = *(const bf16x8*)(&Ks[cur][krow * 64 + (((kg + 4) ^ (krow & 7)) << 3)]);
      s[tt] = __builtin_amdgcn_mfma_f32_16x16x32_bf16(b0, aq0, s[tt], 0, 0, 0);
      s[tt] = __builtin_amdgcn_mfma_f32_16x16x32_bf16(b1, aq1, s[tt], 0, 0, 0);
    }
    __builtin_amdgcn_s_setprio(0);
    const int qq = q0 + w * 16 + row16;
    const int k0 = t * 64;
#pragma unroll
    for (int tt = 0; tt < 4; ++tt) {
      f32x4 pv;
#pragma unroll
      for (int rr = 0; rr < 4; ++rr) pv[rr] = exp2f(s[tt][rr] - lc);
      __builtin_nontemporal_store(
          pv, (f32x4*)(Patt + ((size_t)bh * LL + qq) * LL + k0 + tt * 16 + kg * 4));
      short4 ps;
      ps.x = (short)f2bf(pv[0]); ps.y = (short)f2bf(pv[1]);
      ps.z = (short)f2bf(pv[2]); ps.w = (short)f2bf(pv[3]);
      int c = ((tt * 2 + (kg >> 1)) ^ (row16 & 7));
      *(short4*)(&PsT[w][row16 * 64 + c * 8 + (kg & 1) * 4]) = ps;
    }
    bf16x8 pb0 = *(const bf16x8*)(&PsT[w][row16 * 64 + ((kg ^ (row16 & 7)) << 3)]);
    bf16x8 pb1 = *(const bf16x8*)(&PsT[w][row16 * 64 + (((4 + kg) ^ (row16 & 7)) << 3)]);
    __builtin_amdgcn_s_setprio(1);
#pragma unroll
    for (int td = 0; td < 4; ++td) {
      int trow = td * 16 + row16;
      bf16x8 v0 = *(const bf16x8*)(&Vts[cur][trow * 64 + ((kg ^ (trow & 7)) << 3)]);
      bf16x8 v1 = *(const bf16x8*)(&Vts[cur][trow * 64 + (((kg + 4) ^ (trow & 7)) << 3)]);
      oT[td] = __builtin_amdgcn_mfma_f32_16x16x32_bf16(v0, pb0, oT[td], 0, 0, 0);
      oT[td] = __builtin_amdgcn_mfma_f32_16x16x32_bf16(v1, pb1, oT[td], 0, 0, 0);
    }
    __builtin_amdgcn_s_setprio(0);
    if (t < 15) {
      // retire the 4 stage ops (older); let the 4 nt stores ride the barrier
      asm volatile("s_waitcnt vmcnt(4)" ::: "memory");
      __builtin_amdgcn_s_barrier();
    }
  }

  // reference's bug-compatible recombine: n=bh -> i=n>>3 (n//B), jb=n&7 (n%B)
  const int iblk = bh >> 3;
  const int jb = bh & 7;
  const int qq = q0 + w * 16 + row16;
#pragma unroll
  for (int td = 0; td < 4; ++td) {
    short4 ov;
    ov.x = (short)f2bf(oT[td][0]); ov.y = (short)f2bf(oT[td][1]);
    ov.z = (short)f2bf(oT[td][2]); ov.w = (short)f2bf(oT[td][3]);
    *(short4*)(attb + ((size_t)jb * LL + qq) * FF + iblk * 64 + td * 16 + kg * 4) = ov;
  }
#undef STAGE_K
#undef STAGE_V
}

// ---------------- out projection + bias + residual (BK=64) ------------------
__global__ __launch_bounds__(256) void proj_out(
    const short* __restrict__ A, const short* __restrict__ Bt,
    const float* __restrict__ bias, const short* __restrict__ resid,
    short* __restrict__ xb) {
  const int o = blockIdx.x + (blockIdx.y << 6);
  const int n = ((o & 7) << 6) + (o >> 3);
  const int by = n & 7, bx = n >> 3;

  __shared__ __attribute__((aligned(16))) short As[128 * 64];
  __shared__ __attribute__((aligned(16))) short Bs[128 * 64];

  const int tid = threadIdx.x;
  const int lane = tid & 63, w = tid >> 6;
  const int wr = w >> 1, wc = w & 1;
  const int row16 = lane & 15, kg = lane >> 4;
  const int m0 = bx * 128, n0 = by * 128;

  const f32x4 z4 = {0.f, 0.f, 0.f, 0.f};
  f32x4 acc[4][4];
  for (int i = 0; i < 4; ++i)
    for (int j = 0; j < 4; ++j) acc[i][j] = z4;

  for (int k0 = 0; k0 < FF; k0 += 64) {
#pragma unroll
    for (int rr = 0; rr < 4; ++rr) {
      int e8 = tid + rr * 256;
      int row = e8 >> 3, cs = ((e8 & 7) ^ (row & 7)) * 8;
      GLD_LDS16(A + (size_t)(m0 + row) * FF + k0 + cs, As + e8 * 8);
      GLD_LDS16(Bt + (size_t)(n0 + row) * FF + k0 + cs, Bs + e8 * 8);
    }
    __syncthreads();
#pragma unroll
    for (int kk2 = 0; kk2 < 2; ++kk2) {
      bf16x8 af[4], bfr[4];
#pragma unroll
      for (int i = 0; i < 4; ++i) {
        int ra = wr * 64 + i * 16 + row16;
        int rb = wc * 64 + i * 16 + row16;
        af[i]  = *(const bf16x8*)(As + ra * 64 + ((((kk2 << 2) | kg) ^ (ra & 7)) << 3));
        bfr[i] = *(const bf16x8*)(Bs + rb * 64 + ((((kk2 << 2) | kg) ^ (rb & 7)) << 3));
      }
#pragma unroll
      for (int i = 0; i < 4; ++i)
#pragma unroll
        for (int j = 0; j < 4; ++j)
          acc[i][j] = __builtin_amdgcn_mfma_f32_16x16x32_bf16(af[i], bfr[j], acc[i][j], 0, 0, 0);
    }
    __syncthreads();
  }

#pragma unroll
  for (int i = 0; i < 4; ++i) {
#pragma unroll
    for (int j = 0; j < 4; ++j) {
      int ncol = n0 + wc * 64 + j * 16 + row16;
      float bn = bias[ncol];
#pragma unroll
      for (int rr = 0; rr < 4; ++rr) {
        int m = m0 + wr * 64 + i * 16 + kg * 4 + rr;
        float val = acc[i][j][rr] + bn + bf2f((unsigned short)resid[(size_t)m * FF + ncol]);
        xb[(size_t)m * FF + ncol] = (short)f2bf(val);
      }
    }
  }
}

// ---------------- LayerNorm (bf16 input, fp32 output, nt stores) ------------
__global__ __launch_bounds__(256) void ln_kernel(const short* __restrict__ xb,
                                                 const float* __restrict__ gamma,
                                                 const float* __restrict__ beta,
                                                 float* __restrict__ out) {
  const int row = blockIdx.x;
  const int tid = threadIdx.x;
  const short4 v4 = *(const short4*)(xb + (size_t)row * FF + tid * 4);
  float vx = bf2f((unsigned short)v4.x), vy = bf2f((unsigned short)v4.y);
  float vz = bf2f((unsigned short)v4.z), vw = bf2f((unsigned short)v4.w);
  float s = vx + vy + vz + vw;
  float s2 = vx * vx + vy * vy + vz * vz + vw * vw;
#pragma unroll
  for (int o = 1; o < 64; o <<= 1) {
    s += __shfl_xor(s, o);
    s2 += __shfl_xor(s2, o);
  }
  __shared__ float ss[4], ss2[4];
  int w = tid >> 6, lane = tid & 63;
  if (lane == 0) { ss[w] = s; ss2[w] = s2; }
  __syncthreads();
  s = ss[0] + ss[1] + ss[2] + ss[3];
  s2 = ss2[0] + ss2[1] + ss2[2] + ss2[3];
  float mu = s * (1.0f / 1024.0f);
  float var = s2 * (1.0f / 1024.0f) - mu * mu;
  float rs = rsqrtf(var + 1e-5f);
  float4 g = *(const float4*)(gamma + tid * 4);
  float4 be = *(const float4*)(beta + tid * 4);
  f32x4 o;
  o[0] = (vx - mu) * rs * g.x + be.x;
  o[1] = (vy - mu) * rs * g.y + be.y;
  o[2] = (vz - mu) * rs * g.z + be.z;
  o[3] = (vw - mu) * rs * g.w + be.w;
  __builtin_nontemporal_store(o, (f32x4*)(out + (size_t)row * FF + tid * 4));
}

extern "C" void kernel_launch(void* const* d_in, const int* in_sizes, int n_in,
                              void* d_out, int out_size, void* d_ws, size_t ws_size,
                              hipStream_t stream) {
  const float* q  = (const float*)d_in[0];
  const float* k  = (const float*)d_in[1];
  const float* v  = (const float*)d_in[2];
  const float* Wq = (const float*)d_in[3];
  const float* bq = (const float*)d_in[4];
  const float* Wk = (const float*)d_in[5];
  const float* bk = (const float*)d_in[6];
  const float* Wv = (const float*)d_in[7];
  const float* bv = (const float*)d_in[8];
  const float* Wf = (const float*)d_in[9];
  const float* bf = (const float*)d_in[10];
  const float* gamma = (const float*)d_in[11];
  const float* beta  = (const float*)d_in[12];

  float* out = (float*)d_out;
  float* Patt = out + (size_t)BB * LL * FF;  // raw_att at offset 8M floats

  char* ws = (char*)d_ws;
  const size_t MB = (size_t)1 << 20;
  short* qb = (short*)(ws + 0 * MB);     // [B*L][F] bf16 (x3); qb stays live (residual)
  short* Wb = (short*)(ws + 48 * MB);    // 4 x F*F bf16 (contiguous after activations)
  short* Qh = (short*)(ws + 56 * MB);    // [BH][L][D] bf16
  short* Kh = (short*)(ws + 72 * MB);    // [BH][L][D] bf16
  short* Vt = (short*)(ws + 88 * MB);    // [BH][D][L] bf16 (written by proj z=2)
  short* attb = (short*)(ws + 32 * MB);  // reuse v-bf16 region (dead after proj)
  short* xb = (short*)(ws + 16 * MB);    // reuse k-bf16 region (dead after proj)

  // one fused conversion launch: 3*2^21 + 4*2^18 = 7340032 float4 = 28672 blocks
  cvt_all<<<28672, 256, 0, stream>>>(q, k, v, Wq, Wk, Wv, Wf, qb);

  proj_qkv<<<dim3(64, 8, 3), 256, 0, stream>>>(qb, Wb, bq, bk, bv, Qh);
  attn_kernel<<<dim3(16, 128), 256, 0, stream>>>(Qh, Kh, Vt, Patt, attb);
  proj_out<<<dim3(64, 8), 256, 0, stream>>>(attb, Wb + 3 * (size_t)FF * FF, bf, qb, xb);
  ln_kernel<<<8192, 256, 0, stream>>>(xb, gamma, beta, out);
}

// Round 14
// 281.579 us; speedup vs baseline: 1.7278x; 1.0268x over previous
//
#include <hip/hip_runtime.h>

#define BB 8
#define LL 1024
#define FF 1024
#define HH 16
#define DD 64
#define NBH 128   // B*H

typedef __attribute__((ext_vector_type(8))) short bf16x8;
typedef __attribute__((ext_vector_type(4))) float f32x4;

#define GLD_LDS16(g, l)                                                        \
  __builtin_amdgcn_global_load_lds(                                            \
      (const __attribute__((address_space(1))) unsigned int*)(g),              \
      (__attribute__((address_space(3))) unsigned int*)(l), 16, 0, 0)

__device__ __forceinline__ unsigned short f2bf(float f) {
  unsigned int u = __float_as_uint(f);
  unsigned int r = u + 0x7fffu + ((u >> 16) & 1u);   // RNE
  return (unsigned short)(r >> 16);
}
__device__ __forceinline__ float bf2f(unsigned short s) {
  return __uint_as_float(((unsigned int)s) << 16);
}

// ---------------- fp32 -> bf16 convert (ALL inputs, one launch) -------------
__global__ __launch_bounds__(256) void cvt_all(
    const float* __restrict__ q, const float* __restrict__ k,
    const float* __restrict__ v, const float* __restrict__ w0,
    const float* __restrict__ w1, const float* __restrict__ w2,
    const float* __restrict__ w3, short* __restrict__ dst) {
  const int NA = (BB * LL * FF) / 4;  // 2^21 float4 per activation
  const int NW = (FF * FF) / 4;       // 2^18 float4 per weight
  int i = blockIdx.x * 256 + threadIdx.x;   // exact grid
  const float* src;
  int off;
  if (i < 3 * NA) {
    int z = i >> 21;
    src = (z == 0) ? q : (z == 1) ? k : v;
    off = i - z * NA;
  } else {
    int j = i - 3 * NA;
    int z = j >> 18;
    src = (z == 0) ? w0 : (z == 1) ? w1 : (z == 2) ? w2 : w3;
    off = j - z * NW;
  }
  f32x4 val = __builtin_nontemporal_load((const f32x4*)src + off);
  short4 o;
  o.x = (short)f2bf(val[0]); o.y = (short)f2bf(val[1]);
  o.z = (short)f2bf(val[2]); o.w = (short)f2bf(val[3]);
  ((short4*)dst)[i] = o;
}

// ---------------- QKV projection GEMM (NT, bf16 MFMA, BK=64) ----------------
// XCD swizzle (T1); BK=64. Epilogue stages C through a padded LDS tile for
// coalesced b128 stores; z==2 writes the tile TRANSPOSED so V lands directly
// in [bh][d][l] layout.
__global__ __launch_bounds__(256) void proj_qkv(
    const short* __restrict__ Aall, const short* __restrict__ Wall,
    const float* __restrict__ bq, const float* __restrict__ bk,
    const float* __restrict__ bv, short* __restrict__ Dall) {
  const int o = blockIdx.x + (blockIdx.y << 6) + (blockIdx.z << 9);
  const int n = ((o & 7) * 192) + (o >> 3);
  const int z = n >> 9;
  const int r = n & 511;
  const int by = r & 7, bx = r >> 3;

  const short* A  = Aall + (size_t)z * (BB * LL * FF);
  const short* Bt = Wall + (size_t)z * (FF * FF);
  const float* bias = (z == 0) ? bq : (z == 1) ? bk : bv;
  short* dst = Dall + (size_t)z * ((size_t)NBH * LL * DD);
  // fold 1/sqrt(D) AND log2(e) into Q so softmax uses native exp2
  const float scale = (z == 0) ? 0.125f * 1.44269504088896f : 1.0f;

  __shared__ __attribute__((aligned(16))) short LB[128 * 136];  // 34 KB
  short* As = LB;            // [128][64] swizzled
  short* Bs = LB + 128 * 64; // [128][64] swizzled

  const int tid = threadIdx.x;
  const int lane = tid & 63, w = tid >> 6;
  const int wr = w >> 1, wc = w & 1;
  const int row16 = lane & 15, kg = lane >> 4;
  const int m0 = bx * 128, n0 = by * 128;

  const f32x4 z4 = {0.f, 0.f, 0.f, 0.f};
  f32x4 acc[4][4];
  for (int i = 0; i < 4; ++i)
    for (int j = 0; j < 4; ++j) acc[i][j] = z4;

  for (int k0 = 0; k0 < FF; k0 += 64) {
#pragma unroll
    for (int rr = 0; rr < 4; ++rr) {
      int e8 = tid + rr * 256;
      int row = e8 >> 3, cs = ((e8 & 7) ^ (row & 7)) * 8;
      GLD_LDS16(A + (size_t)(m0 + row) * FF + k0 + cs, As + e8 * 8);
      GLD_LDS16(Bt + (size_t)(n0 + row) * FF + k0 + cs, Bs + e8 * 8);
    }
    __syncthreads();
#pragma unroll
    for (int kk2 = 0; kk2 < 2; ++kk2) {
      bf16x8 af[4], bfr[4];
#pragma unroll
      for (int i = 0; i < 4; ++i) {
        int ra = wr * 64 + i * 16 + row16;
        int rb = wc * 64 + i * 16 + row16;
        af[i]  = *(const bf16x8*)(As + ra * 64 + ((((kk2 << 2) | kg) ^ (ra & 7)) << 3));
        bfr[i] = *(const bf16x8*)(Bs + rb * 64 + ((((kk2 << 2) | kg) ^ (rb & 7)) << 3));
      }
#pragma unroll
      for (int i = 0; i < 4; ++i)
#pragma unroll
        for (int j = 0; j < 4; ++j)
          acc[i][j] = __builtin_amdgcn_mfma_f32_16x16x32_bf16(af[i], bfr[j], acc[i][j], 0, 0, 0);
    }
    __syncthreads();
  }

  // ---- epilogue through LDS tile LB[128][136] ----
  const int z2 = (z == 2);
#pragma unroll
  for (int i = 0; i < 4; ++i) {
#pragma unroll
    for (int j = 0; j < 4; ++j) {
      int nl = wc * 64 + j * 16 + row16;
      float bn = bias[n0 + nl];
#pragma unroll
      for (int rr = 0; rr < 4; ++rr) {
        int ml = wr * 64 + i * 16 + kg * 4 + rr;
        float val = (acc[i][j][rr] + bn) * scale;
        int rrow = z2 ? nl : ml, ccol = z2 ? ml : nl;
        LB[rrow * 136 + ccol] = (short)f2bf(val);
      }
    }
  }
  __syncthreads();
  const int b = m0 >> 10;
  const int lbase = m0 & 1023;
#pragma unroll
  for (int rr = 0; rr < 8; ++rr) {
    int e = tid + rr * 256;          // 0..2047
    int row = e >> 4, c8 = e & 15;
    uint4 val = *(const uint4*)(LB + row * 136 + c8 * 8);
    if (!z2) {
      int l = lbase + row;
      int h = (n0 + c8 * 8) >> 6, d = (c8 & 7) * 8;
      *(uint4*)(dst + (((size_t)(b * HH + h)) * LL + l) * DD + d) = val;
    } else {
      int h = (n0 + row) >> 6, d = (n0 + row) & 63;
      int l = lbase + c8 * 8;
      *(uint4*)(dst + (((size_t)(b * HH + h)) * DD + d) * LL + l) = val;
    }
  }
}

// ---------------- fused attention (per (bh, 64-row q-block)) ----------------
// R9 schedule + two occupancy/latency tweaks (no sync-structure change):
//  - PsT aliases Qs (disjoint lifetimes: Qs dead after aq loads, PsT first
//    written in phase 2) -> LDS 48->40 KB -> 4 blocks/CU (16 waves).
//  - Phase 1 prefetch 3-deep over FOUR K-buffers (Ks[0],Ks[1],Vts[0],Vts[1]
//    — V unused in phase 1); steady-state vmcnt(4).
// Phase 2 unchanged: 1-deep K/V dbuf, vmcnt(4) lets nt Patt stores ride.
__global__ __launch_bounds__(256, 4) void attn_kernel(
    const short* __restrict__ Qh, const short* __restrict__ Kh,
    const short* __restrict__ Vt, float* __restrict__ Patt,
    short* __restrict__ attb) {
  const int o = blockIdx.x + (blockIdx.y << 4);
  const int n = ((o & 7) << 8) + (o >> 3);
  const int bh = n >> 4;
  const int q0 = (n & 15) * 64;
  const int tid = threadIdx.x;
  const int lane = tid & 63, w = tid >> 6;
  const int row16 = lane & 15, kg = lane >> 4;

  __shared__ __attribute__((aligned(16))) short Qs[64 * 64];      // aliased by PsT in phase 2
  __shared__ __attribute__((aligned(16))) short Ks[2][64 * 64];
  __shared__ __attribute__((aligned(16))) short Vts[2][64 * 64];

  short* PsTw = Qs + w * (16 * 64);  // per-wave P^T tile, aliases dead Qs

  // phase-1 K quad-buffer: slots 2,3 borrow Vts[0],Vts[1] (unused in phase 1)
  auto kbuf4 = [&](int i) -> short* {
    return (i == 0) ? &Ks[0][0] : (i == 1) ? &Ks[1][0]
         : (i == 2) ? &Vts[0][0] : &Vts[1][0];
  };

#define STAGE_K(tt, dstp)                                                      \
  {                                                                            \
    int e8a = tid, rowa = e8a >> 3, c8a = (e8a & 7) ^ (rowa & 7);              \
    GLD_LDS16(Kh + ((size_t)bh * LL + (tt) * 64 + rowa) * DD + c8a * 8,        \
              (dstp) + e8a * 8);                                               \
    int e8b = tid + 256, rowb = e8b >> 3, c8b = (e8b & 7) ^ (rowb & 7);        \
    GLD_LDS16(Kh + ((size_t)bh * LL + (tt) * 64 + rowb) * DD + c8b * 8,        \
              (dstp) + e8b * 8);                                               \
  }
#define STAGE_V(tt, dstp)                                                      \
  {                                                                            \
    int e8a = tid, rowa = e8a >> 3, c8a = (e8a & 7) ^ (rowa & 7);              \
    GLD_LDS16(Vt + ((size_t)bh * DD + rowa) * LL + (tt) * 64 + c8a * 8,        \
              (dstp) + e8a * 8);                                               \
    int e8b = tid + 256, rowb = e8b >> 3, c8b = (e8b & 7) ^ (rowb & 7);        \
    GLD_LDS16(Vt + ((size_t)bh * DD + rowb) * LL + (tt) * 64 + c8b * 8,        \
              (dstp) + e8b * 8);                                               \
  }

  {  // Q stage (2 ops) + K tiles 0,1,2 (6 ops)
    int e8a = tid, rowa = e8a >> 3, c8a = (e8a & 7) ^ (rowa & 7);
    GLD_LDS16(Qh + ((size_t)bh * LL + q0 + rowa) * DD + c8a * 8, Qs + e8a * 8);
    int e8b = tid + 256, rowb = e8b >> 3, c8b = (e8b & 7) ^ (rowb & 7);
    GLD_LDS16(Qh + ((size_t)bh * LL + q0 + rowb) * DD + c8b * 8, Qs + e8b * 8);
  }
  STAGE_K(0, kbuf4(0));
  STAGE_K(1, kbuf4(1));
  STAGE_K(2, kbuf4(2));
  // need Q + K0 complete; K1,K2 (4 newest ops) may stay outstanding
  asm volatile("s_waitcnt vmcnt(4)" ::: "memory");
  __builtin_amdgcn_s_barrier();

  const int qrow = w * 16 + row16;
  bf16x8 aq0 = *(const bf16x8*)(Qs + qrow * 64 + ((kg ^ (qrow & 7)) << 3));
  bf16x8 aq1 = *(const bf16x8*)(Qs + qrow * 64 + (((kg + 4) ^ (qrow & 7)) << 3));

  const f32x4 z4 = {0.f, 0.f, 0.f, 0.f};
  float lsum = 0.f;

  // phase 1: row sums of exp2(S') — 3-deep prefetch over 4 buffers
  for (int t = 0; t < 16; ++t) {
    const short* kb = kbuf4(t & 3);
    if (t < 13) {
      short* kd = kbuf4((t + 3) & 3);
      STAGE_K(t + 3, kd);
    }
    f32x4 s[4] = {z4, z4, z4, z4};
    __builtin_amdgcn_s_setprio(1);
#pragma unroll
    for (int tt = 0; tt < 4; ++tt) {
      int krow = tt * 16 + row16;
      bf16x8 b0 = *(const bf16x8*)(kb + krow * 64 + ((kg ^ (krow & 7)) << 3));
      bf16x8 b1 = *(const bf16x8*)(kb + krow * 64 + (((kg + 4) ^ (krow & 7)) << 3));
      s[tt] = __builtin_amdgcn_mfma_f32_16x16x32_bf16(b0, aq0, s[tt], 0, 0, 0);
      s[tt] = __builtin_amdgcn_mfma_f32_16x16x32_bf16(b1, aq1, s[tt], 0, 0, 0);
    }
    __builtin_amdgcn_s_setprio(0);
#pragma unroll
    for (int tt = 0; tt < 4; ++tt)
#pragma unroll
      for (int rr = 0; rr < 4; ++rr) lsum += exp2f(s[tt][rr]);
    if (t < 13) {
      asm volatile("s_waitcnt vmcnt(4)" ::: "memory");  // t+1 ready; t+2,t+3 in flight
    } else if (t == 13) {
      asm volatile("s_waitcnt vmcnt(2)" ::: "memory");  // t+1 ready; t+2 in flight
    } else {
      asm volatile("s_waitcnt vmcnt(0)" ::: "memory");
    }
    __builtin_amdgcn_s_barrier();
  }
  lsum += __shfl_xor(lsum, 16);
  lsum += __shfl_xor(lsum, 32);
  const float lc = __log2f(lsum);   // normalize inside the exponent

  f32x4 oT[4] = {z4, z4, z4, z4};

  // phase 2: recompute S^T, P = exp2(s - lc), nt-store Patt, O^T += V^T P
  STAGE_K(0, &Ks[0][0]);
  STAGE_V(0, &Vts[0][0]);
  asm volatile("s_waitcnt vmcnt(0)" ::: "memory");
  __builtin_amdgcn_s_barrier();
  for (int t = 0; t < 16; ++t) {
    const int cur = t & 1;
    if (t < 15) {
      STAGE_K(t + 1, &Ks[cur ^ 1][0]);
      STAGE_V(t + 1, &Vts[cur ^ 1][0]);
    }
    f32x4 s[4] = {z4, z4, z4, z4};
    __builtin_amdgcn_s_setprio(1);
#pragma unroll
    for (int tt = 0; tt < 4; ++tt) {
      int krow = tt * 16 + row16;
      bf16x8 b0 = *(const bf16x8*)(&Ks[cur][krow * 64 + ((kg ^ (krow & 7)) << 3)]);
      bf16x8 b1 = *(const bf16x8*)(&Ks[cur][krow * 64 + (((kg + 4) ^ (krow & 7)) << 3)]);
      s[tt] = __builtin_amdgcn_mfma_f32_16x16x32_bf16(b0, aq0, s[tt], 0, 0, 0);
      s[tt] = __builtin_amdgcn_mfma_f32_16x16x32_bf16(b1, aq1, s[tt], 0, 0, 0);
    }
    __builtin_amdgcn_s_setprio(0);
    const int qq = q0 + w * 16 + row16;
    const int k0 = t * 64;
#pragma unroll
    for (int tt = 0; tt < 4; ++tt) {
      f32x4 pv;
#pragma unroll
      for (int rr = 0; rr < 4; ++rr) pv[rr] = exp2f(s[tt][rr] - lc);
      __builtin_nontemporal_store(
          pv, (f32x4*)(Patt + ((size_t)bh * LL + qq) * LL + k0 + tt * 16 + kg * 4));
      short4 ps;
      ps.x = (short)f2bf(pv[0]); ps.y = (short)f2bf(pv[1]);
      ps.z = (short)f2bf(pv[2]); ps.w = (short)f2bf(pv[3]);
      int c = ((tt * 2 + (kg >> 1)) ^ (row16 & 7));
      *(short4*)(&PsTw[row16 * 64 + c * 8 + (kg & 1) * 4]) = ps;
    }
    bf16x8 pb0 = *(const bf16x8*)(&PsTw[row16 * 64 + ((kg ^ (row16 & 7)) << 3)]);
    bf16x8 pb1 = *(const bf16x8*)(&PsTw[row16 * 64 + (((4 + kg) ^ (row16 & 7)) << 3)]);
    __builtin_amdgcn_s_setprio(1);
#pragma unroll
    for (int td = 0; td < 4; ++td) {
      int trow = td * 16 + row16;
      bf16x8 v0 = *(const bf16x8*)(&Vts[cur][trow * 64 + ((kg ^ (trow & 7)) << 3)]);
      bf16x8 v1 = *(const bf16x8*)(&Vts[cur][trow * 64 + (((kg + 4) ^ (trow & 7)) << 3)]);
      oT[td] = __builtin_amdgcn_mfma_f32_16x16x32_bf16(v0, pb0, oT[td], 0, 0, 0);
      oT[td] = __builtin_amdgcn_mfma_f32_16x16x32_bf16(v1, pb1, oT[td], 0, 0, 0);
    }
    __builtin_amdgcn_s_setprio(0);
    if (t < 15) {
      // retire the 4 stage ops (older); let the 4 nt stores ride the barrier
      asm volatile("s_waitcnt vmcnt(4)" ::: "memory");
      __builtin_amdgcn_s_barrier();
    }
  }

  // reference's bug-compatible recombine: n=bh -> i=n>>3 (n//B), jb=n&7 (n%B)
  const int iblk = bh >> 3;
  const int jb = bh & 7;
  const int qq = q0 + w * 16 + row16;
#pragma unroll
  for (int td = 0; td < 4; ++td) {
    short4 ov;
    ov.x = (short)f2bf(oT[td][0]); ov.y = (short)f2bf(oT[td][1]);
    ov.z = (short)f2bf(oT[td][2]); ov.w = (short)f2bf(oT[td][3]);
    *(short4*)(attb + ((size_t)jb * LL + qq) * FF + iblk * 64 + td * 16 + kg * 4) = ov;
  }
#undef STAGE_K
#undef STAGE_V
}

// ---------------- out projection + bias + residual (BK=64) ------------------
__global__ __launch_bounds__(256) void proj_out(
    const short* __restrict__ A, const short* __restrict__ Bt,
    const float* __restrict__ bias, const short* __restrict__ resid,
    short* __restrict__ xb) {
  const int o = blockIdx.x + (blockIdx.y << 6);
  const int n = ((o & 7) << 6) + (o >> 3);
  const int by = n & 7, bx = n >> 3;

  __shared__ __attribute__((aligned(16))) short As[128 * 64];
  __shared__ __attribute__((aligned(16))) short Bs[128 * 64];

  const int tid = threadIdx.x;
  const int lane = tid & 63, w = tid >> 6;
  const int wr = w >> 1, wc = w & 1;
  const int row16 = lane & 15, kg = lane >> 4;
  const int m0 = bx * 128, n0 = by * 128;

  const f32x4 z4 = {0.f, 0.f, 0.f, 0.f};
  f32x4 acc[4][4];
  for (int i = 0; i < 4; ++i)
    for (int j = 0; j < 4; ++j) acc[i][j] = z4;

  for (int k0 = 0; k0 < FF; k0 += 64) {
#pragma unroll
    for (int rr = 0; rr < 4; ++rr) {
      int e8 = tid + rr * 256;
      int row = e8 >> 3, cs = ((e8 & 7) ^ (row & 7)) * 8;
      GLD_LDS16(A + (size_t)(m0 + row) * FF + k0 + cs, As + e8 * 8);
      GLD_LDS16(Bt + (size_t)(n0 + row) * FF + k0 + cs, Bs + e8 * 8);
    }
    __syncthreads();
#pragma unroll
    for (int kk2 = 0; kk2 < 2; ++kk2) {
      bf16x8 af[4], bfr[4];
#pragma unroll
      for (int i = 0; i < 4; ++i) {
        int ra = wr * 64 + i * 16 + row16;
        int rb = wc * 64 + i * 16 + row16;
        af[i]  = *(const bf16x8*)(As + ra * 64 + ((((kk2 << 2) | kg) ^ (ra & 7)) << 3));
        bfr[i] = *(const bf16x8*)(Bs + rb * 64 + ((((kk2 << 2) | kg) ^ (rb & 7)) << 3));
      }
#pragma unroll
      for (int i = 0; i < 4; ++i)
#pragma unroll
        for (int j = 0; j < 4; ++j)
          acc[i][j] = __builtin_amdgcn_mfma_f32_16x16x32_bf16(af[i], bfr[j], acc[i][j], 0, 0, 0);
    }
    __syncthreads();
  }

#pragma unroll
  for (int i = 0; i < 4; ++i) {
#pragma unroll
    for (int j = 0; j < 4; ++j) {
      int ncol = n0 + wc * 64 + j * 16 + row16;
      float bn = bias[ncol];
#pragma unroll
      for (int rr = 0; rr < 4; ++rr) {
        int m = m0 + wr * 64 + i * 16 + kg * 4 + rr;
        float val = acc[i][j][rr] + bn + bf2f((unsigned short)resid[(size_t)m * FF + ncol]);
        xb[(size_t)m * FF + ncol] = (short)f2bf(val);
      }
    }
  }
}

// ---------------- LayerNorm (bf16 input, fp32 output, nt stores) ------------
__global__ __launch_bounds__(256) void ln_kernel(const short* __restrict__ xb,
                                                 const float* __restrict__ gamma,
                                                 const float* __restrict__ beta,
                                                 float* __restrict__ out) {
  const int row = blockIdx.x;
  const int tid = threadIdx.x;
  const short4 v4 = *(const short4*)(xb + (size_t)row * FF + tid * 4);
  float vx = bf2f((unsigned short)v4.x), vy = bf2f((unsigned short)v4.y);
  float vz = bf2f((unsigned short)v4.z), vw = bf2f((unsigned short)v4.w);
  float s = vx + vy + vz + vw;
  float s2 = vx * vx + vy * vy + vz * vz + vw * vw;
#pragma unroll
  for (int o = 1; o < 64; o <<= 1) {
    s += __shfl_xor(s, o);
    s2 += __shfl_xor(s2, o);
  }
  __shared__ float ss[4], ss2[4];
  int w = tid >> 6, lane = tid & 63;
  if (lane == 0) { ss[w] = s; ss2[w] = s2; }
  __syncthreads();
  s = ss[0] + ss[1] + ss[2] + ss[3];
  s2 = ss2[0] + ss2[1] + ss2[2] + ss2[3];
  float mu = s * (1.0f / 1024.0f);
  float var = s2 * (1.0f / 1024.0f) - mu * mu;
  float rs = rsqrtf(var + 1e-5f);
  float4 g = *(const float4*)(gamma + tid * 4);
  float4 be = *(const float4*)(beta + tid * 4);
  f32x4 o;
  o[0] = (vx - mu) * rs * g.x + be.x;
  o[1] = (vy - mu) * rs * g.y + be.y;
  o[2] = (vz - mu) * rs * g.z + be.z;
  o[3] = (vw - mu) * rs * g.w + be.w;
  __builtin_nontemporal_store(o, (f32x4*)(out + (size_t)row * FF + tid * 4));
}

extern "C" void kernel_launch(void* const* d_in, const int* in_sizes, int n_in,
                              void* d_out, int out_size, void* d_ws, size_t ws_size,
                              hipStream_t stream) {
  const float* q  = (const float*)d_in[0];
  const float* k  = (const float*)d_in[1];
  const float* v  = (const float*)d_in[2];
  const float* Wq = (const float*)d_in[3];
  const float* bq = (const float*)d_in[4];
  const float* Wk = (const float*)d_in[5];
  const float* bk = (const float*)d_in[6];
  const float* Wv = (const float*)d_in[7];
  const float* bv = (const float*)d_in[8];
  const float* Wf = (const float*)d_in[9];
  const float* bf = (const float*)d_in[10];
  const float* gamma = (const float*)d_in[11];
  const float* beta  = (const float*)d_in[12];

  float* out = (float*)d_out;
  float* Patt = out + (size_t)BB * LL * FF;  // raw_att at offset 8M floats

  char* ws = (char*)d_ws;
  const size_t MB = (size_t)1 << 20;
  short* qb = (short*)(ws + 0 * MB);     // [B*L][F] bf16 (x3); qb stays live (residual)
  short* Wb = (short*)(ws + 48 * MB);    // 4 x F*F bf16 (contiguous after activations)
  short* Qh = (short*)(ws + 56 * MB);    // [BH][L][D] bf16
  short* Kh = (short*)(ws + 72 * MB);    // [BH][L][D] bf16
  short* Vt = (short*)(ws + 88 * MB);    // [BH][D][L] bf16 (written by proj z=2)
  short* attb = (short*)(ws + 32 * MB);  // reuse v-bf16 region (dead after proj)
  short* xb = (short*)(ws + 16 * MB);    // reuse k-bf16 region (dead after proj)

  // one fused conversion launch: 3*2^21 + 4*2^18 = 7340032 float4 = 28672 blocks
  cvt_all<<<28672, 256, 0, stream>>>(q, k, v, Wq, Wk, Wv, Wf, qb);

  proj_qkv<<<dim3(64, 8, 3), 256, 0, stream>>>(qb, Wb, bq, bk, bv, Qh);
  attn_kernel<<<dim3(16, 128), 256, 0, stream>>>(Qh, Kh, Vt, Patt, attb);
  proj_out<<<dim3(64, 8), 256, 0, stream>>>(attb, Wb + 3 * (size_t)FF * FF, bf, qb, xb);
  ln_kernel<<<8192, 256, 0, stream>>>(xb, gamma, beta, out);
}